// Round 9
// baseline (46.716 us; speedup 1.0000x reference)
//
#include <hip/hip_runtime.h>
#include <hip/hip_bf16.h>

typedef __attribute__((ext_vector_type(8))) short bf16x8;
typedef __attribute__((ext_vector_type(4))) float f32x4;

#define HW_   252
#define PLANE 63504            // 252*252
#define NCH   32
#define WS_NEED (25600u * 2u)  // packed weights only

__device__ __forceinline__ unsigned short f2bf(float f) {
    unsigned u = __builtin_bit_cast(unsigned, f);
    u += 0x7FFFu + ((u >> 16) & 1u);   // round-to-nearest-even
    return (unsigned short)(u >> 16);
}

// padded coord p -> source index: circular mod 256, then reflect(p-2)
__device__ __forceinline__ int padmap(int p) {
    int t = (p & 255) - 2;
    t = t < 0 ? -t : t;
    return t > 251 ? 502 - t : t;
}

// wp[t][o][ci] = bf16(w[o][ci][4-da][4-db]), t = da*5+db
__global__ void pack_w_kernel(const float* __restrict__ w, unsigned short* __restrict__ wp) {
    int e = blockIdx.x * 256 + threadIdx.x;   // [25][32][32]
    if (e >= 25600) return;
    int ci = e & 31;
    int o  = (e >> 5) & 31;
    int t  = e >> 10;
    int da = t / 5, db = t - da * 5;
    wp[e] = f2bf(w[((o * 32 + ci) * 5 + (4 - da)) * 5 + (4 - db)]);
}

// Fused conv v2: NCHW fp32 in, reflect+circular pad on the fly.
// Staging is T14 issue-early/consume-late: ALL 80 loads batch-issued into
// v[10][8] registers (one latency exposure), then cvt + linear ds_write_b128.
// No shared index maps -> LDS exactly 40960 B -> 4 blocks/CU.
__global__ __launch_bounds__(256, 4) void conv_fused_v2(
    const float* __restrict__ x,
    const unsigned short* __restrict__ wp,
    float* __restrict__ out)
{
    __shared__ unsigned short xl[32 * 20 * 32];   // 40960 B, linear [pr][col][g][ci8]

    const int tid  = threadIdx.x;
    const int orig = blockIdx.x;                  // 1152 blocks = 8 XCD * 144
    const int b    = orig & 7;                    // XCD-bijective: image b per XCD
    const int idx  = orig >> 3;                   // 0..143
    const int rt   = idx >> 4;                    // 0..8
    const int ct   = idx & 15;                    // 0..15
    const int i0 = rt * 28, j0 = ct * 16;

    // ---- stage patch 32x20x32: batch-issue all 80 loads, then convert ----
    float v[10][8];                               // 80 VGPR in-flight buffer
    {
        const float* xb = x + (size_t)b * NCH * PLANE;
        #pragma unroll
        for (int it = 0; it < 10; ++it) {
            int task = it * 256 + tid;
            int g    = task & 3;
            int pc   = task >> 2;          // pr*20 + col
            int pr   = pc / 20;
            int col  = pc - pr * 20;
            const float* src = xb + (size_t)(g * 8) * PLANE
                                  + (size_t)padmap(i0 + 1 + pr) * HW_
                                  + padmap(j0 + 1 + col);
            #pragma unroll
            for (int q = 0; q < 8; ++q)
                v[it][q] = src[q * PLANE];
        }
    }
    #pragma unroll
    for (int it = 0; it < 10; ++it) {
        int task = it * 256 + tid;
        unsigned short pk[8];
        #pragma unroll
        for (int q = 0; q < 8; ++q)
            pk[q] = __builtin_bit_cast(unsigned short,
                        __float2bfloat16(v[it][q]));
        *reinterpret_cast<uint4*>(reinterpret_cast<char*>(xl) + task * 16)
            = *reinterpret_cast<const uint4*>(pk);
    }
    __syncthreads();

    const int lane = tid & 63;
    const int wid  = tid >> 6;
    const int lm   = lane & 15;    // o-within-16 (A) / pixel col (B,D)
    const int lg   = lane >> 4;    // k-group
    const int rowb = wid * 7;      // wave's first local output row

    const char* xlb = reinterpret_cast<const char*>(xl);
    const char* wb  = reinterpret_cast<const char*>(wp);
    const int afix  = (lm << 6) + (lg << 4);
    const int j     = j0 + lm;

    f32x4 acc[7][2];
    #pragma unroll
    for (int r = 0; r < 7; ++r) {
        acc[r][0] = (f32x4){0.f, 0.f, 0.f, 0.f};
        acc[r][1] = (f32x4){0.f, 0.f, 0.f, 0.f};
    }

    #pragma unroll
    for (int db = 0; db < 5; ++db) {
        bf16x8 a[5][2];
        #pragma unroll
        for (int da = 0; da < 5; ++da) {
            const char* ap = wb + ((da * 5 + db) << 11) + afix;
            a[da][0] = *reinterpret_cast<const bf16x8*>(ap);
            a[da][1] = *reinterpret_cast<const bf16x8*>(ap + 1024);
        }

        #pragma unroll
        for (int l = 0; l < 11; ++l) {
            // patch row rowb+l, cols lm+db: contiguous 1KB per wave, conflict-free
            bf16x8 bf = *reinterpret_cast<const bf16x8*>(
                xlb + (rowb + l) * 1280 + ((lm + db) << 6) + (lg << 4));
            #pragma unroll
            for (int da = 0; da < 5; ++da) {
                const int r = l - da;
                if (r >= 0 && r < 7) {
                    acc[r][0] = __builtin_amdgcn_mfma_f32_16x16x32_bf16(
                        a[da][0], bf, acc[r][0], 0, 0, 0);
                    acc[r][1] = __builtin_amdgcn_mfma_f32_16x16x32_bf16(
                        a[da][1], bf, acc[r][1], 0, 0, 0);
                }
            }
        }
    }

    // store: o = mt*16 + lg*4 + q, col = lm (rows always in-bounds; 252=9*28)
    #pragma unroll
    for (int r = 0; r < 7; ++r) {
        const int i = i0 + rowb + r;
        if (j < HW_) {
            #pragma unroll
            for (int mt = 0; mt < 2; ++mt) {
                size_t rowoff = ((size_t)(b * NCH + mt * 16 + lg * 4)) * PLANE
                              + (size_t)i * HW_ + j;
                #pragma unroll
                for (int q = 0; q < 4; ++q)
                    out[rowoff + (size_t)q * PLANE] = acc[r][mt][q];
            }
        }
    }
}

// ---------------- fallback (ws too small): R2-style single kernel ----------------
__global__ __launch_bounds__(256) void conv_mfma_fb(
    const float* __restrict__ x,
    const float* __restrict__ w_raw,
    float* __restrict__ out)
{
    __shared__ unsigned short xl[12800];
    __shared__ unsigned short wl[25600];
    __shared__ int rmap[20], cmap[20];

    const int tid = threadIdx.x;
    const int bid = blockIdx.x;
    const int b  = bid >> 8;
    const int rt = (bid >> 4) & 15;
    const int ct = bid & 15;
    const int i0 = rt * 16, j0 = ct * 16;

    if (tid < 40) {
        int k    = tid < 20 ? tid : tid - 20;
        int base = tid < 20 ? i0  : j0;
        int r = (base + 1 + k) & 255;
        int t = r - 2;
        int m = t < 0 ? -t : (t > 251 ? 502 - t : t);
        if (tid < 20) rmap[k] = m; else cmap[k] = m;
    }
    for (int e = tid; e < 25600; e += 256) {
        int o   = e / 800;
        int rem = e - o * 800;
        int ci  = rem / 25;
        int kd  = rem - ci * 25;
        wl[(24 - kd) * 1024 + o * 32 + ci] = f2bf(w_raw[e]);
    }
    __syncthreads();

    for (int task = tid; task < 1600; task += 256) {
        int col = task % 20;
        int g   = (task / 20) & 3;
        int row = task / 80;
        const float* src = x + (size_t)(b * NCH + g * 8) * PLANE
                             + (size_t)rmap[row] * HW_ + cmap[col];
        unsigned short pk[8];
        #pragma unroll
        for (int q = 0; q < 8; ++q) pk[q] = f2bf(src[q * PLANE]);
        int off = ((row * 20 + col) << 6) + ((g ^ (col & 3)) << 4);
        *reinterpret_cast<uint4*>(reinterpret_cast<char*>(xl) + off)
            = *reinterpret_cast<const uint4*>(pk);
    }
    __syncthreads();

    const int lane  = tid & 63;
    const int wid   = tid >> 6;
    const int lm    = lane & 15;
    const int lg    = lane >> 4;
    const int rbase = wid * 4;

    f32x4 acc[4][2];
    #pragma unroll
    for (int rr = 0; rr < 4; ++rr) {
        acc[rr][0] = (f32x4){0.f, 0.f, 0.f, 0.f};
        acc[rr][1] = (f32x4){0.f, 0.f, 0.f, 0.f};
    }

    const char* wbase = (const char*)wl;
    const int afix = (lm << 6) + (lg << 4);
    const char* xlb = reinterpret_cast<const char*>(xl);

    #pragma unroll
    for (int da = 0; da < 5; ++da) {
        #pragma unroll
        for (int db = 0; db < 5; ++db) {
            const int t = da * 5 + db;
            bf16x8 a0 = *reinterpret_cast<const bf16x8*>(wbase + (t << 11) + afix);
            bf16x8 a1 = *reinterpret_cast<const bf16x8*>(wbase + (t << 11) + 1024 + afix);
            const int col  = lm + db;
            const int coff = (col << 6) + ((lg ^ (col & 3)) << 4);
            #pragma unroll
            for (int rr = 0; rr < 4; ++rr) {
                const int row = rbase + rr + da;
                bf16x8 bf = *reinterpret_cast<const bf16x8*>(xlb + row * 1280 + coff);
                acc[rr][0] = __builtin_amdgcn_mfma_f32_16x16x32_bf16(a0, bf, acc[rr][0], 0, 0, 0);
                acc[rr][1] = __builtin_amdgcn_mfma_f32_16x16x32_bf16(a1, bf, acc[rr][1], 0, 0, 0);
            }
        }
    }

    const int j = j0 + lm;
    #pragma unroll
    for (int rr = 0; rr < 4; ++rr) {
        const int i = i0 + rbase + rr;
        if (i < HW_ && j < HW_) {
            size_t rowoff = (size_t)(b * NCH) * PLANE + (size_t)i * HW_ + j;
            #pragma unroll
            for (int mt = 0; mt < 2; ++mt)
                #pragma unroll
                for (int q = 0; q < 4; ++q) {
                    int o = mt * 16 + lg * 4 + q;
                    out[rowoff + (size_t)o * PLANE] = acc[rr][mt][q];
                }
        }
    }
}

extern "C" void kernel_launch(void* const* d_in, const int* in_sizes, int n_in,
                              void* d_out, int out_size, void* d_ws, size_t ws_size,
                              hipStream_t stream) {
    const float* x = (const float*)d_in[0];
    const float* w = (const float*)d_in[1];
    float* out = (float*)d_out;

    if (ws_size >= WS_NEED) {
        unsigned short* wp = (unsigned short*)d_ws;
        hipLaunchKernelGGL(pack_w_kernel, dim3(100), dim3(256), 0, stream, w, wp);
        hipLaunchKernelGGL(conv_fused_v2, dim3(1152), dim3(256), 0, stream,
                           x, (const unsigned short*)wp, out);
    } else {
        hipLaunchKernelGGL(conv_mfma_fb, dim3(2048), dim3(256), 0, stream, x, w, out);
    }
}